// Round 1
// baseline (609.578 us; speedup 1.0000x reference)
//
#include <hip/hip_runtime.h>
#include <math.h>

#define HEADS 8
#define DK 32
#define B_ 4
#define C_ 256
#define NVOX 1728   // 12*12*12

// ---------------------------------------------------------------------------
// pos[h][d][n] = rel_d[h][d][di] + rel_w[h][d][wi] + rel_h[h][d][hi]
// n = (di*12 + wi)*12 + hi  (matches x spatial flattening)
// ---------------------------------------------------------------------------
__global__ void pos_kernel(const float* __restrict__ rel_d,
                           const float* __restrict__ rel_h,
                           const float* __restrict__ rel_w,
                           float* __restrict__ pos) {
    int idx = blockIdx.x * 256 + threadIdx.x;   // 8*32*1728 = 442368 total
    if (idx >= HEADS * DK * NVOX) return;
    int n  = idx % NVOX;
    int hd = idx / NVOX;          // h*32 + d
    int di = n / 144;
    int wi = (n / 12) % 12;
    int hi = n % 12;
    pos[idx] = rel_d[hd * 12 + di] + rel_w[hd * 12 + wi] + rel_h[hd * 12 + hi];
}

// ---------------------------------------------------------------------------
// Fused QKV projection.  proj[m][b][o][n] = sum_c x[b][c][n] * w_m[o][c] + b_m[o]
// layout: proj[((m*B_ + b)*C_ + o)*NVOX + n]
// grid: (ceil(N/256)=7, 64 o-groups of 4, B).  x reads coalesced over n,
// w reads are block-uniform -> scalar loads.
// ---------------------------------------------------------------------------
__global__ void proj_kernel(const float* __restrict__ x,
                            const float* __restrict__ wq, const float* __restrict__ bq,
                            const float* __restrict__ wk, const float* __restrict__ bk,
                            const float* __restrict__ wv, const float* __restrict__ bv,
                            float* __restrict__ proj) {
    int n  = blockIdx.x * 256 + threadIdx.x;
    int o0 = blockIdx.y * 4;
    int b  = blockIdx.z;
    bool valid = (n < NVOX);
    int nn = valid ? n : 0;
    const float* xb = x + (size_t)b * C_ * NVOX + nn;

    float acc[3][4] = {};
    #pragma unroll 4
    for (int c = 0; c < C_; c++) {
        float xv = xb[(size_t)c * NVOX];
        #pragma unroll
        for (int oo = 0; oo < 4; oo++) {
            int widx = (o0 + oo) * C_ + c;
            acc[0][oo] = fmaf(xv, wq[widx], acc[0][oo]);
            acc[1][oo] = fmaf(xv, wk[widx], acc[1][oo]);
            acc[2][oo] = fmaf(xv, wv[widx], acc[2][oo]);
        }
    }
    if (!valid) return;
    #pragma unroll
    for (int oo = 0; oo < 4; oo++) {
        int o = o0 + oo;
        proj[((size_t)(0 * B_ + b) * C_ + o) * NVOX + n] = acc[0][oo] + bq[o];
        proj[((size_t)(1 * B_ + b) * C_ + o) * NVOX + n] = acc[1][oo] + bk[o];
        proj[((size_t)(2 * B_ + b) * C_ + o) * NVOX + n] = acc[2][oo] + bv[o];
    }
}

// ---------------------------------------------------------------------------
// Flash attention, fp32 vector ALU.
// Per (b,h): S[i,j] = sum_{dd<64} Q'[dd][i] * K'[dd][j]
//   Q'[0:32] = q rows i, Q'[32:64] = pos rows i
//   K'[0:32] = k cols j, K'[32:64] = q cols j
// online softmax over j, O[d][i] += P[i][j] * v[d][j], final /l.
// block 256, grid (27 i-tiles, HEADS, B).  Tiles 64x64.
// ---------------------------------------------------------------------------
__global__ __launch_bounds__(256, 2)
void attn_kernel(const float* __restrict__ proj,
                 const float* __restrict__ pos,
                 float* __restrict__ out) {
    int it = blockIdx.x;
    int h  = blockIdx.y;
    int b  = blockIdx.z;
    int t  = threadIdx.x;

    __shared__ __align__(16) float sQ[64][64];
    __shared__ __align__(16) float sK[64][64];
    __shared__ __align__(16) float sVT[64][34];   // v transposed: [j][d], pad 34
    __shared__ __align__(16) float sPT[64][68];   // P transposed: [j][i], pad 68
    __shared__ float sM[64];
    __shared__ float sL[64];
    __shared__ float sAlpha[64];

    const float* q  = proj + ((size_t)(0 * B_ + b) * C_ + h * DK) * NVOX;  // q[d][n]
    const float* k  = proj + ((size_t)(1 * B_ + b) * C_ + h * DK) * NVOX;
    const float* v  = proj + ((size_t)(2 * B_ + b) * C_ + h * DK) * NVOX;
    const float* ph = pos + (size_t)h * DK * NVOX;                          // pos[d][n]

    int i_base = it * 64;

    // load Q' tile (once per block): 64x64
    for (int e = t; e < 4096; e += 256) {
        int dd = e >> 6, i = e & 63;
        float val = (dd < 32) ? q[(size_t)dd * NVOX + i_base + i]
                              : ph[(size_t)(dd - 32) * NVOX + i_base + i];
        sQ[dd][i] = val;
    }
    if (t < 64) { sM[t] = -INFINITY; sL[t] = 0.f; }

    // S-phase mapping: 4x4 micro-tile
    int rg = t >> 4, cg = t & 15;       // rows i0s..i0s+3, cols j0s..j0s+3
    int i0s = rg * 4, j0s = cg * 4;
    // PV-phase mapping: 4i x 2d micro-tile
    int ig = t & 15, dg = t >> 4;
    int i0p = ig * 4, d0 = dg * 2;

    float O[4][2] = {};

    for (int jt = 0; jt < 27; jt++) {
        int j_base = jt * 64;
        // ---- load K' tile and V^T tile ----
        for (int e = t; e < 4096; e += 256) {
            int dd = e >> 6, j = e & 63;
            float val = (dd < 32) ? k[(size_t)dd * NVOX + j_base + j]
                                  : q[(size_t)(dd - 32) * NVOX + j_base + j];
            sK[dd][j] = val;
        }
        for (int e = t; e < 2048; e += 256) {
            int d = e >> 6, j = e & 63;
            sVT[j][d] = v[(size_t)d * NVOX + j_base + j];
        }
        __syncthreads();

        // ---- scores: 4x4 micro-tile over dd=0..63 ----
        float s[4][4] = {};
        for (int dd = 0; dd < 64; dd++) {
            float4 q4 = *(const float4*)&sQ[dd][i0s];
            float4 k4 = *(const float4*)&sK[dd][j0s];
            float qa[4] = {q4.x, q4.y, q4.z, q4.w};
            float ka[4] = {k4.x, k4.y, k4.z, k4.w};
            #pragma unroll
            for (int r = 0; r < 4; r++)
                #pragma unroll
                for (int c = 0; c < 4; c++)
                    s[r][c] = fmaf(qa[r], ka[c], s[r][c]);
        }

        // ---- online softmax (rows spread across 16 lanes of same wave) ----
        float mnew[4], alpha[4], psum[4];
        #pragma unroll
        for (int r = 0; r < 4; r++) {
            float mx = fmaxf(fmaxf(s[r][0], s[r][1]), fmaxf(s[r][2], s[r][3]));
            #pragma unroll
            for (int msk = 1; msk <= 8; msk <<= 1)
                mx = fmaxf(mx, __shfl_xor(mx, msk));
            float mold = sM[i0s + r];
            float mn = fmaxf(mold, mx);
            float al = __expf(mold - mn);
            float ps = 0.f;
            #pragma unroll
            for (int c = 0; c < 4; c++) {
                float p = __expf(s[r][c] - mn);
                s[r][c] = p;
                ps += p;
            }
            #pragma unroll
            for (int msk = 1; msk <= 8; msk <<= 1)
                ps += __shfl_xor(ps, msk);
            mnew[r] = mn; alpha[r] = al; psum[r] = ps;
        }
        // write P^T tile: sPT[j][i] = P[i][j]
        #pragma unroll
        for (int c = 0; c < 4; c++) {
            float4 w4 = make_float4(s[0][c], s[1][c], s[2][c], s[3][c]);
            *(float4*)&sPT[j0s + c][i0s] = w4;
        }
        if (cg == 0) {
            #pragma unroll
            for (int r = 0; r < 4; r++) {
                sM[i0s + r] = mnew[r];
                sAlpha[i0s + r] = alpha[r];
                sL[i0s + r] = sL[i0s + r] * alpha[r] + psum[r];
            }
        }
        __syncthreads();

        // ---- PV update ----
        #pragma unroll
        for (int ii = 0; ii < 4; ii++) {
            float al = sAlpha[i0p + ii];
            O[ii][0] *= al;
            O[ii][1] *= al;
        }
        for (int j = 0; j < 64; j++) {
            float4 p4 = *(const float4*)&sPT[j][i0p];
            float2 v2 = *(const float2*)&sVT[j][d0];
            float pa[4] = {p4.x, p4.y, p4.z, p4.w};
            #pragma unroll
            for (int ii = 0; ii < 4; ii++) {
                O[ii][0] = fmaf(pa[ii], v2.x, O[ii][0]);
                O[ii][1] = fmaf(pa[ii], v2.y, O[ii][1]);
            }
        }
        __syncthreads();   // protect sK/sVT/sPT for next iteration's loads
    }

    // ---- epilogue: out[b][h*32+d][i] = O / l ----
    float* outp = out + (size_t)((b * HEADS + h) * DK) * NVOX;
    #pragma unroll
    for (int ii = 0; ii < 4; ii++) {
        float inv = 1.f / sL[i0p + ii];
        int i_glob = i_base + i0p + ii;
        outp[(size_t)(d0 + 0) * NVOX + i_glob] = O[ii][0] * inv;
        outp[(size_t)(d0 + 1) * NVOX + i_glob] = O[ii][1] * inv;
    }
}

// ---------------------------------------------------------------------------
extern "C" void kernel_launch(void* const* d_in, const int* in_sizes, int n_in,
                              void* d_out, int out_size, void* d_ws, size_t ws_size,
                              hipStream_t stream) {
    const float* x     = (const float*)d_in[0];
    const float* wq    = (const float*)d_in[1];
    const float* bq    = (const float*)d_in[2];
    const float* wk    = (const float*)d_in[3];
    const float* bk    = (const float*)d_in[4];
    const float* wv    = (const float*)d_in[5];
    const float* bv    = (const float*)d_in[6];
    const float* rel_d = (const float*)d_in[7];
    const float* rel_h = (const float*)d_in[8];
    const float* rel_w = (const float*)d_in[9];
    float* out = (float*)d_out;

    float* ws   = (float*)d_ws;
    float* proj = ws;                                     // 3*B*C*N floats
    float* pos  = ws + (size_t)3 * B_ * C_ * NVOX;        // H*DK*N floats

    pos_kernel<<<dim3((HEADS * DK * NVOX + 255) / 256), dim3(256), 0, stream>>>(
        rel_d, rel_h, rel_w, pos);

    dim3 pgrid((NVOX + 255) / 256, C_ / 4, B_);
    proj_kernel<<<pgrid, dim3(256), 0, stream>>>(x, wq, bq, wk, bk, wv, bv, proj);

    dim3 agrid(NVOX / 64, HEADS, B_);
    attn_kernel<<<agrid, dim3(256), 0, stream>>>(proj, pos, out);
}

// Round 2
// 402.026 us; speedup vs baseline: 1.5163x; 1.5163x over previous
//
#include <hip/hip_runtime.h>
#include <math.h>

#define HEADS 8
#define DK 32
#define B_ 4
#define C_ 256
#define NVOX 1728   // 12*12*12
#define DE 64       // effective head dim: Q'=[q;pos], K'=[k;q]
#define PITCH 72    // LDS pitch in bf16 elements (pad 64 -> 72)

typedef short bf16x8 __attribute__((ext_vector_type(8)));
typedef float f32x4 __attribute__((ext_vector_type(4)));

__device__ inline short f2bf(float x) {
    unsigned u = __float_as_uint(x);
    unsigned r = u + 0x7fffu + ((u >> 16) & 1u);
    return (short)(r >> 16);
}
__device__ inline float bf2f(short h) {
    return __uint_as_float(((unsigned)(unsigned short)h) << 16);
}

// ---------------------------------------------------------------------------
// pos[h][d][n] = rel_d + rel_w + rel_h,  n = (di*12 + wi)*12 + hi
// ---------------------------------------------------------------------------
__global__ void pos_kernel(const float* __restrict__ rel_d,
                           const float* __restrict__ rel_h,
                           const float* __restrict__ rel_w,
                           float* __restrict__ pos) {
    int idx = blockIdx.x * 256 + threadIdx.x;
    if (idx >= HEADS * DK * NVOX) return;
    int n  = idx % NVOX;
    int hd = idx / NVOX;
    int di = n / 144;
    int wi = (n / 12) % 12;
    int hi = n % 12;
    pos[idx] = rel_d[hd * 12 + di] + rel_w[hd * 12 + wi] + rel_h[hd * 12 + hi];
}

// ---------------------------------------------------------------------------
// Fused QKV projection (fp32 vector GEMM).  proj[m][b][o][n]
// ---------------------------------------------------------------------------
__global__ void proj_kernel(const float* __restrict__ x,
                            const float* __restrict__ wq, const float* __restrict__ bq,
                            const float* __restrict__ wk, const float* __restrict__ bk,
                            const float* __restrict__ wv, const float* __restrict__ bv,
                            float* __restrict__ proj) {
    int n  = blockIdx.x * 256 + threadIdx.x;
    int o0 = blockIdx.y * 4;
    int b  = blockIdx.z;
    bool valid = (n < NVOX);
    int nn = valid ? n : 0;
    const float* xb = x + (size_t)b * C_ * NVOX + nn;

    float acc[3][4] = {};
    #pragma unroll 4
    for (int c = 0; c < C_; c++) {
        float xv = xb[(size_t)c * NVOX];
        #pragma unroll
        for (int oo = 0; oo < 4; oo++) {
            int widx = (o0 + oo) * C_ + c;
            acc[0][oo] = fmaf(xv, wq[widx], acc[0][oo]);
            acc[1][oo] = fmaf(xv, wk[widx], acc[1][oo]);
            acc[2][oo] = fmaf(xv, wv[widx], acc[2][oo]);
        }
    }
    if (!valid) return;
    #pragma unroll
    for (int oo = 0; oo < 4; oo++) {
        int o = o0 + oo;
        proj[((size_t)(0 * B_ + b) * C_ + o) * NVOX + n] = acc[0][oo] + bq[o];
        proj[((size_t)(1 * B_ + b) * C_ + o) * NVOX + n] = acc[1][oo] + bk[o];
        proj[((size_t)(2 * B_ + b) * C_ + o) * NVOX + n] = acc[2][oo] + bv[o];
    }
}

// ---------------------------------------------------------------------------
// Prep: build transposed bf16 hi/lo operand tensors.
//   QhiT/QloT/KhiT/KloT: [b,h][n][64]   (n-major so attention stages via uint4)
//   Vbf:                 [b,h][d][n]
// Q'[dd] = q[dd] (dd<32) else pos[dd-32];  K'[dd] = k[dd] (dd<32) else q[dd-32]
// ---------------------------------------------------------------------------
__global__ void prep_kernel(const float* __restrict__ proj,
                            const float* __restrict__ pos,
                            short* __restrict__ QhiT, short* __restrict__ QloT,
                            short* __restrict__ KhiT, short* __restrict__ KloT,
                            short* __restrict__ Vbf) {
    int t  = threadIdx.x;
    int dd = t & 63;
    int n  = blockIdx.x * 4 + (t >> 6);
    int h  = blockIdx.y, b = blockIdx.z;
    int bh = b * HEADS + h;
    const float* q  = proj + ((size_t)(0 * B_ + b) * C_ + h * DK) * NVOX;
    const float* k  = proj + ((size_t)(1 * B_ + b) * C_ + h * DK) * NVOX;
    const float* v  = proj + ((size_t)(2 * B_ + b) * C_ + h * DK) * NVOX;
    const float* ph = pos + (size_t)h * DK * NVOX;

    float qv = (dd < DK) ? q[(size_t)dd * NVOX + n] : ph[(size_t)(dd - DK) * NVOX + n];
    float kv = (dd < DK) ? k[(size_t)dd * NVOX + n] : q[(size_t)(dd - DK) * NVOX + n];
    size_t o = ((size_t)bh * NVOX + n) * DE + dd;
    short qhv = f2bf(qv);
    QhiT[o] = qhv;
    QloT[o] = f2bf(qv - bf2f(qhv));
    short khv = f2bf(kv);
    KhiT[o] = khv;
    KloT[o] = f2bf(kv - bf2f(khv));
    if (dd < DK)
        Vbf[((size_t)bh * DK + dd) * NVOX + n] = f2bf(v[(size_t)dd * NVOX + n]);
}

// ---------------------------------------------------------------------------
// Flash attention with bf16 MFMA (16x16x32), hi/lo-split QK' logits.
// Block = 256 (4 waves); i-tile 64 (16 rows per wave); j-tiles of 64.
// ---------------------------------------------------------------------------
struct SMem {
    short Qhi[64][PITCH];
    short Qlo[64][PITCH];
    union {
        struct { short Khi[64][PITCH]; short Klo[64][PITCH]; } k;
        float Out[DK][PITCH];
    } u;
    short V[DK][PITCH];
    short P[64][PITCH];
};

__global__ __launch_bounds__(256, 3)
void attn_kernel(const short* __restrict__ QhiT, const short* __restrict__ QloT,
                 const short* __restrict__ KhiT, const short* __restrict__ KloT,
                 const short* __restrict__ Vbf, float* __restrict__ out) {
    __shared__ SMem sm;
    int it = blockIdx.x, h = blockIdx.y, b = blockIdx.z;
    int bh = b * HEADS + h;
    int t = threadIdx.x;
    int w = t >> 6, l = t & 63, lg = l >> 4, ln = l & 15;
    int islab = w * 16;
    int i_base = it * 64;

    const short* Qh = QhiT + (size_t)bh * NVOX * DE;
    const short* Qlp = QloT + (size_t)bh * NVOX * DE;
    const short* Kh = KhiT + (size_t)bh * NVOX * DE;
    const short* Klp = KloT + (size_t)bh * NVOX * DE;
    const short* Vp = Vbf + (size_t)bh * DK * NVOX;

    // ---- stage Q' tiles (once) ----
    for (int e = t; e < 512; e += 256) {
        int row = e >> 3, c = (e & 7) * 8;
        *(uint4*)&sm.Qhi[row][c] = *(const uint4*)&Qh[(size_t)(i_base + row) * DE + c];
        *(uint4*)&sm.Qlo[row][c] = *(const uint4*)&Qlp[(size_t)(i_base + row) * DE + c];
    }
    __syncthreads();

    // A-fragments for Q' (reused across all j-tiles)
    bf16x8 qh[2], ql[2];
    #pragma unroll
    for (int ks = 0; ks < 2; ks++) {
        qh[ks] = *(const bf16x8*)&sm.Qhi[islab + ln][ks * 32 + lg * 8];
        ql[ks] = *(const bf16x8*)&sm.Qlo[islab + ln][ks * 32 + lg * 8];
    }

    float mrow[4], lrow[4];
    #pragma unroll
    for (int r = 0; r < 4; r++) { mrow[r] = -INFINITY; lrow[r] = 0.f; }
    f32x4 O0 = {0.f, 0.f, 0.f, 0.f}, O1 = {0.f, 0.f, 0.f, 0.f};

    #pragma unroll 1
    for (int jt = 0; jt < 27; jt++) {
        int jb = jt * 64;
        // ---- stage K' hi/lo (8KB each) + V (4KB) ----
        for (int e = t; e < 512; e += 256) {
            int row = e >> 3, c = (e & 7) * 8;
            *(uint4*)&sm.u.k.Khi[row][c] = *(const uint4*)&Kh[(size_t)(jb + row) * DE + c];
            *(uint4*)&sm.u.k.Klo[row][c] = *(const uint4*)&Klp[(size_t)(jb + row) * DE + c];
        }
        {
            int d = t >> 3, c = (t & 7) * 8;
            *(uint4*)&sm.V[d][c] = *(const uint4*)&Vp[(size_t)d * NVOX + jb + c];
        }
        __syncthreads();

        // ---- S = Q'^T K' over 4 j-subtiles, hi/lo split (3 MFMA per k-step) ----
        f32x4 sc[4];
        #pragma unroll
        for (int js = 0; js < 4; js++) {
            f32x4 s = {0.f, 0.f, 0.f, 0.f};
            #pragma unroll
            for (int ks = 0; ks < 2; ks++) {
                bf16x8 kh = *(const bf16x8*)&sm.u.k.Khi[js * 16 + ln][ks * 32 + lg * 8];
                bf16x8 kl = *(const bf16x8*)&sm.u.k.Klo[js * 16 + ln][ks * 32 + lg * 8];
                s = __builtin_amdgcn_mfma_f32_16x16x32_bf16(qh[ks], kh, s, 0, 0, 0);
                s = __builtin_amdgcn_mfma_f32_16x16x32_bf16(ql[ks], kh, s, 0, 0, 0);
                s = __builtin_amdgcn_mfma_f32_16x16x32_bf16(qh[ks], kl, s, 0, 0, 0);
            }
            sc[js] = s;
        }

        // ---- online softmax (rows live in 16-lane groups; wave-local) ----
        float alpha[4], p[4][4];
        #pragma unroll
        for (int r = 0; r < 4; r++) {
            float mx = fmaxf(fmaxf(sc[0][r], sc[1][r]), fmaxf(sc[2][r], sc[3][r]));
            #pragma unroll
            for (int msk = 1; msk <= 8; msk <<= 1) mx = fmaxf(mx, __shfl_xor(mx, msk));
            float mn = fmaxf(mrow[r], mx);
            alpha[r] = __expf(mrow[r] - mn);
            mrow[r] = mn;
            float ps = 0.f;
            #pragma unroll
            for (int js = 0; js < 4; js++) { p[js][r] = __expf(sc[js][r] - mn); ps += p[js][r]; }
            #pragma unroll
            for (int msk = 1; msk <= 8; msk <<= 1) ps += __shfl_xor(ps, msk);
            lrow[r] = lrow[r] * alpha[r] + ps;
        }

        // ---- P: C-layout -> LDS [i][j] (per-wave-private rows; no barrier) ----
        #pragma unroll
        for (int js = 0; js < 4; js++)
            #pragma unroll
            for (int r = 0; r < 4; r++)
                sm.P[islab + lg * 4 + r][js * 16 + ln] = f2bf(p[js][r]);

        #pragma unroll
        for (int r = 0; r < 4; r++) { O0[r] *= alpha[r]; O1[r] *= alpha[r]; }

        // ---- PV: O[16 i][32 d] += P[16x64] * V^T[64x32] ----
        #pragma unroll
        for (int ks = 0; ks < 2; ks++) {
            bf16x8 pa = *(const bf16x8*)&sm.P[islab + ln][ks * 32 + lg * 8];
            bf16x8 v0 = *(const bf16x8*)&sm.V[ln][ks * 32 + lg * 8];
            bf16x8 v1 = *(const bf16x8*)&sm.V[16 + ln][ks * 32 + lg * 8];
            O0 = __builtin_amdgcn_mfma_f32_16x16x32_bf16(pa, v0, O0, 0, 0, 0);
            O1 = __builtin_amdgcn_mfma_f32_16x16x32_bf16(pa, v1, O1, 0, 0, 0);
        }
        __syncthreads();   // protect K'/V staging for next tile
    }

    // ---- epilogue: Out[d][i] = O/l, staged through LDS for coalesced store ----
    float inv[4];
    #pragma unroll
    for (int r = 0; r < 4; r++) inv[r] = 1.f / lrow[r];
    #pragma unroll
    for (int r = 0; r < 4; r++) {
        sm.u.Out[ln][islab + lg * 4 + r]      = O0[r] * inv[r];
        sm.u.Out[16 + ln][islab + lg * 4 + r] = O1[r] * inv[r];
    }
    __syncthreads();
    float* outp = out + (size_t)bh * DK * NVOX;
    for (int e = t; e < DK * 64; e += 256) {
        int d = e >> 6, i = e & 63;
        outp[(size_t)d * NVOX + i_base + i] = sm.u.Out[d][i];
    }
}

// ---------------------------------------------------------------------------
extern "C" void kernel_launch(void* const* d_in, const int* in_sizes, int n_in,
                              void* d_out, int out_size, void* d_ws, size_t ws_size,
                              hipStream_t stream) {
    const float* x     = (const float*)d_in[0];
    const float* wq    = (const float*)d_in[1];
    const float* bq    = (const float*)d_in[2];
    const float* wk    = (const float*)d_in[3];
    const float* bk    = (const float*)d_in[4];
    const float* wv    = (const float*)d_in[5];
    const float* bv    = (const float*)d_in[6];
    const float* rel_d = (const float*)d_in[7];
    const float* rel_h = (const float*)d_in[8];
    const float* rel_w = (const float*)d_in[9];
    float* out = (float*)d_out;

    float* proj = (float*)d_ws;                               // 5,308,416 f
    float* pos  = proj + (size_t)3 * B_ * C_ * NVOX;          // 442,368 f
    short* QhiT = (short*)(pos + (size_t)HEADS * DK * NVOX);
    size_t qksz = (size_t)B_ * HEADS * NVOX * DE;             // 3,538,944 shorts
    short* QloT = QhiT + qksz;
    short* KhiT = QloT + qksz;
    short* KloT = KhiT + qksz;
    short* Vbf  = KloT + qksz;                                // 1,769,472 shorts

    pos_kernel<<<dim3((HEADS * DK * NVOX + 255) / 256), dim3(256), 0, stream>>>(
        rel_d, rel_h, rel_w, pos);

    dim3 pgrid((NVOX + 255) / 256, C_ / 4, B_);
    proj_kernel<<<pgrid, dim3(256), 0, stream>>>(x, wq, bq, wk, bk, wv, bv, proj);

    dim3 prgrid(NVOX / 4, HEADS, B_);
    prep_kernel<<<prgrid, dim3(256), 0, stream>>>(proj, pos, QhiT, QloT, KhiT, KloT, Vbf);

    dim3 agrid(NVOX / 64, HEADS, B_);
    attn_kernel<<<agrid, dim3(256), 0, stream>>>(QhiT, QloT, KhiT, KloT, Vbf, out);
}

// Round 3
// 269.967 us; speedup vs baseline: 2.2580x; 1.4892x over previous
//
#include <hip/hip_runtime.h>
#include <math.h>

#define HEADS 8
#define DK 32
#define B_ 4
#define C_ 256
#define NVOX 1728   // 12*12*12
#define DE 64       // effective head dim: Q'=[q;pos], K'=[k;q]
#define PITCH 72    // LDS pitch (shorts): 144 B = 9*16 -> 16B-aligned rows, stride 4 banks
#define LOG2E 1.44269504088896f

typedef short bf16x8 __attribute__((ext_vector_type(8)));
typedef float f32x16 __attribute__((ext_vector_type(16)));

__device__ inline short f2bf(float x) {
    unsigned u = __float_as_uint(x);
    unsigned r = u + 0x7fffu + ((u >> 16) & 1u);
    return (short)(r >> 16);
}
__device__ inline float bf2f(short h) {
    return __uint_as_float(((unsigned)(unsigned short)h) << 16);
}

// ---------------------------------------------------------------------------
// Fused QKV projection (fp32 vector GEMM).  proj[m][b][o][n]
// ---------------------------------------------------------------------------
__global__ void proj_kernel(const float* __restrict__ x,
                            const float* __restrict__ wq, const float* __restrict__ bq,
                            const float* __restrict__ wk, const float* __restrict__ bk,
                            const float* __restrict__ wv, const float* __restrict__ bv,
                            float* __restrict__ proj) {
    int n  = blockIdx.x * 256 + threadIdx.x;
    int o0 = blockIdx.y * 4;
    int b  = blockIdx.z;
    bool valid = (n < NVOX);
    int nn = valid ? n : 0;
    const float* xb = x + (size_t)b * C_ * NVOX + nn;

    float acc[3][4] = {};
    #pragma unroll 4
    for (int c = 0; c < C_; c++) {
        float xv = xb[(size_t)c * NVOX];
        #pragma unroll
        for (int oo = 0; oo < 4; oo++) {
            int widx = (o0 + oo) * C_ + c;
            acc[0][oo] = fmaf(xv, wq[widx], acc[0][oo]);
            acc[1][oo] = fmaf(xv, wk[widx], acc[1][oo]);
            acc[2][oo] = fmaf(xv, wv[widx], acc[2][oo]);
        }
    }
    if (!valid) return;
    #pragma unroll
    for (int oo = 0; oo < 4; oo++) {
        int o = o0 + oo;
        proj[((size_t)(0 * B_ + b) * C_ + o) * NVOX + n] = acc[0][oo] + bq[o];
        proj[((size_t)(1 * B_ + b) * C_ + o) * NVOX + n] = acc[1][oo] + bk[o];
        proj[((size_t)(2 * B_ + b) * C_ + o) * NVOX + n] = acc[2][oo] + bv[o];
    }
}

// ---------------------------------------------------------------------------
// Prep: pos computed on the fly; emit transposed bf16 hi/lo Q'/K' + bf16 V.
//   QhiT/QloT/KhiT/KloT: [b,h][n][64]   Vbf: [b,h][d][n]
// ---------------------------------------------------------------------------
__global__ void prep_kernel(const float* __restrict__ proj,
                            const float* __restrict__ rel_d,
                            const float* __restrict__ rel_h,
                            const float* __restrict__ rel_w,
                            short* __restrict__ QhiT, short* __restrict__ QloT,
                            short* __restrict__ KhiT, short* __restrict__ KloT,
                            short* __restrict__ Vbf) {
    int t  = threadIdx.x;
    int dd = t & 63;
    int n  = blockIdx.x * 4 + (t >> 6);
    int h  = blockIdx.y, b = blockIdx.z;
    int bh = b * HEADS + h;
    const float* q = proj + ((size_t)(0 * B_ + b) * C_ + h * DK) * NVOX;
    const float* k = proj + ((size_t)(1 * B_ + b) * C_ + h * DK) * NVOX;
    const float* v = proj + ((size_t)(2 * B_ + b) * C_ + h * DK) * NVOX;

    float qv, kv;
    if (dd < DK) {
        qv = q[(size_t)dd * NVOX + n];
        kv = k[(size_t)dd * NVOX + n];
    } else {
        int di = n / 144, wi = (n / 12) % 12, hi = n % 12;
        int hd = h * DK + (dd - DK);
        qv = rel_d[hd * 12 + di] + rel_w[hd * 12 + wi] + rel_h[hd * 12 + hi];
        kv = q[(size_t)(dd - DK) * NVOX + n];
    }
    size_t o = ((size_t)bh * NVOX + n) * DE + dd;
    short qhv = f2bf(qv);
    QhiT[o] = qhv;
    QloT[o] = f2bf(qv - bf2f(qhv));
    short khv = f2bf(kv);
    KhiT[o] = khv;
    KloT[o] = f2bf(kv - bf2f(khv));
    if (dd < DK)
        Vbf[((size_t)bh * DK + dd) * NVOX + n] = f2bf(v[(size_t)dd * NVOX + n]);
}

// ---------------------------------------------------------------------------
// Flash attention, 32x32x16 bf16 MFMA, S^T orientation.
// Block = 192 (3 waves x 32 i-rows = 96 i per block); 18 i-tiles; j-tiles of 64.
// S^T: D[m=j][n=i] = sum_dd K'[j][dd] * Q'[i][dd]   (A=K', B=Q')
// PV:  O^T[m=d][n=i] = sum_j  Vt[d][j]  * P[i][j]   (A=Vt,  B=P)
// ---------------------------------------------------------------------------
struct SMem {
    short Khi[64][PITCH];
    short Klo[64][PITCH];
    short V[DK][PITCH];
    short P[96][PITCH];
};

__device__ inline f32x16 mfma32(bf16x8 a, bf16x8 b, f32x16 c) {
    return __builtin_amdgcn_mfma_f32_32x32x16_bf16(a, b, c, 0, 0, 0);
}

__global__ __launch_bounds__(192, 3)
void attn_kernel(const short* __restrict__ QhiT, const short* __restrict__ QloT,
                 const short* __restrict__ KhiT, const short* __restrict__ KloT,
                 const short* __restrict__ Vbf, float* __restrict__ out) {
    __shared__ SMem sm;
    int it = blockIdx.x, h = blockIdx.y, b = blockIdx.z;
    int bh = b * HEADS + h;
    int t = threadIdx.x;
    int w  = t >> 6;        // wave 0..2
    int l  = t & 63;
    int ln = l & 31;        // lane-in-half: i column / A-row index
    int hv = l >> 5;        // half-wave: k-subgroup
    int i_loc  = w * 32 + ln;
    int i_glob = it * 96 + i_loc;

    const short* Qh = QhiT + (size_t)bh * NVOX * DE;
    const short* Ql = QloT + (size_t)bh * NVOX * DE;
    const short* Kh = KhiT + (size_t)bh * NVOX * DE;
    const short* Kl = KloT + (size_t)bh * NVOX * DE;
    const short* Vp = Vbf  + (size_t)bh * DK * NVOX;

    // Q' B-fragments straight from global (once): B[n=i][k=dd]
    bf16x8 qfh[4], qfl[4];
    #pragma unroll
    for (int ks = 0; ks < 4; ks++) {
        size_t off = (size_t)i_glob * DE + ks * 16 + hv * 8;
        qfh[ks] = *(const bf16x8*)&Qh[off];
        qfl[ks] = *(const bf16x8*)&Ql[off];
    }

    float mL = -INFINITY;   // running max, log2e-scaled
    float lsum = 0.f;
    f32x16 O;
    #pragma unroll
    for (int r = 0; r < 16; r++) O[r] = 0.f;

    #pragma unroll 1
    for (int jt = 0; jt < 27; jt++) {
        int jb = jt * 64;
        __syncthreads();    // everyone done reading previous K/V
        for (int e = t; e < 512; e += 192) {
            int row = e >> 3, c = (e & 7) * 8;
            *(uint4*)&sm.Khi[row][c] = *(const uint4*)&Kh[(size_t)(jb + row) * DE + c];
            *(uint4*)&sm.Klo[row][c] = *(const uint4*)&Kl[(size_t)(jb + row) * DE + c];
        }
        for (int e = t; e < 256; e += 192) {
            int d = e >> 3, c = (e & 7) * 8;
            *(uint4*)&sm.V[d][c] = *(const uint4*)&Vp[(size_t)d * NVOX + jb + c];
        }
        __syncthreads();

        // ---- S^T: two 32x32 j-subtiles, hi/lo split ----
        f32x16 sc[2];
        #pragma unroll
        for (int js = 0; js < 2; js++) {
            f32x16 s;
            #pragma unroll
            for (int r = 0; r < 16; r++) s[r] = 0.f;
            #pragma unroll
            for (int ks = 0; ks < 4; ks++) {
                bf16x8 kh = *(const bf16x8*)&sm.Khi[js * 32 + ln][ks * 16 + hv * 8];
                bf16x8 kl = *(const bf16x8*)&sm.Klo[js * 32 + ln][ks * 16 + hv * 8];
                s = mfma32(kh, qfh[ks], s);
                s = mfma32(kh, qfl[ks], s);
                s = mfma32(kl, qfh[ks], s);
            }
            sc[js] = s;
        }

        // ---- online softmax over j (i = ln fixed per lane; 1 shuffle) ----
        float mx = sc[0][0];
        #pragma unroll
        for (int js = 0; js < 2; js++)
            #pragma unroll
            for (int r = 0; r < 16; r++) mx = fmaxf(mx, sc[js][r]);
        mx = fmaxf(mx, __shfl_xor(mx, 32));
        float mLn = fmaxf(mL, mx * LOG2E);
        float alpha = exp2f(mL - mLn);
        mL = mLn;
        float ps = 0.f;
        #pragma unroll
        for (int js = 0; js < 2; js++)
            #pragma unroll
            for (int r = 0; r < 16; r++) {
                float p = exp2f(fmaf(sc[js][r], LOG2E, -mLn));
                sc[js][r] = p;
                ps += p;
            }
        ps += __shfl_xor(ps, 32);
        lsum = lsum * alpha + ps;

        // ---- P -> LDS [i][j]: reg-group g holds 4 consecutive j -> b64 writes
        #pragma unroll
        for (int js = 0; js < 2; js++)
            #pragma unroll
            for (int g = 0; g < 4; g++) {
                unsigned u0 = __float_as_uint(sc[js][4 * g + 0]) + 0x8000u;
                unsigned u1 = __float_as_uint(sc[js][4 * g + 1]) + 0x8000u;
                unsigned u2 = __float_as_uint(sc[js][4 * g + 2]) + 0x8000u;
                unsigned u3 = __float_as_uint(sc[js][4 * g + 3]) + 0x8000u;
                uint2 pk;
                pk.x = __builtin_amdgcn_perm(u1, u0, 0x07060302);
                pk.y = __builtin_amdgcn_perm(u3, u2, 0x07060302);
                *(uint2*)&sm.P[i_loc][js * 32 + g * 8 + hv * 4] = pk;
            }

        // ---- O^T += Vt * P  (wave-private P rows; no barrier needed) ----
        #pragma unroll
        for (int r = 0; r < 16; r++) O[r] *= alpha;
        #pragma unroll
        for (int ks = 0; ks < 4; ks++) {
            bf16x8 va = *(const bf16x8*)&sm.V[ln][ks * 16 + hv * 8];
            bf16x8 pb = *(const bf16x8*)&sm.P[i_loc][ks * 16 + hv * 8];
            O = mfma32(va, pb, O);
        }
    }

    // ---- epilogue: out[d][i] = O^T/l, direct stores (32 consecutive i/row) ----
    float inv = 1.f / lsum;
    float* outp = out + (size_t)bh * DK * NVOX;
    #pragma unroll
    for (int r = 0; r < 16; r++) {
        int d = (r & 3) + 8 * (r >> 2) + 4 * hv;
        outp[(size_t)d * NVOX + i_glob] = O[r] * inv;
    }
}

// ---------------------------------------------------------------------------
extern "C" void kernel_launch(void* const* d_in, const int* in_sizes, int n_in,
                              void* d_out, int out_size, void* d_ws, size_t ws_size,
                              hipStream_t stream) {
    const float* x     = (const float*)d_in[0];
    const float* wq    = (const float*)d_in[1];
    const float* bq    = (const float*)d_in[2];
    const float* wk    = (const float*)d_in[3];
    const float* bk    = (const float*)d_in[4];
    const float* wv    = (const float*)d_in[5];
    const float* bv    = (const float*)d_in[6];
    const float* rel_d = (const float*)d_in[7];
    const float* rel_h = (const float*)d_in[8];
    const float* rel_w = (const float*)d_in[9];
    float* out = (float*)d_out;

    float* proj = (float*)d_ws;                               // 3*B*C*N floats
    short* QhiT = (short*)(proj + (size_t)3 * B_ * C_ * NVOX);
    size_t qksz = (size_t)B_ * HEADS * NVOX * DE;             // 3,538,944 shorts
    short* QloT = QhiT + qksz;
    short* KhiT = QloT + qksz;
    short* KloT = KhiT + qksz;
    short* Vbf  = KloT + qksz;

    dim3 pgrid((NVOX + 255) / 256, C_ / 4, B_);
    proj_kernel<<<pgrid, dim3(256), 0, stream>>>(x, wq, bq, wk, bk, wv, bv, proj);

    dim3 prgrid(NVOX / 4, HEADS, B_);
    prep_kernel<<<prgrid, dim3(256), 0, stream>>>(proj, rel_d, rel_h, rel_w,
                                                  QhiT, QloT, KhiT, KloT, Vbf);

    dim3 agrid(NVOX / 96, HEADS, B_);
    attn_kernel<<<agrid, dim3(192), 0, stream>>>(QhiT, QloT, KhiT, KloT, Vbf, out);
}

// Round 4
// 244.686 us; speedup vs baseline: 2.4913x; 1.1033x over previous
//
#include <hip/hip_runtime.h>
#include <math.h>

#define HEADS 8
#define DK 32
#define B_ 4
#define C_ 256
#define NVOX 1728   // 12*12*12
#define DE 64       // effective head dim: Q'=[q;pos], K'=[k;q]
#define PITCH 72    // LDS pitch (shorts): 144 B rows
#define LOG2E 1.44269504088896f

typedef short bf16x8 __attribute__((ext_vector_type(8)));
typedef float f32x16 __attribute__((ext_vector_type(16)));

__device__ inline short f2bf(float x) {
    unsigned u = __float_as_uint(x);
    unsigned r = u + 0x7fffu + ((u >> 16) & 1u);
    return (short)(r >> 16);
}
__device__ inline float bf2f(short h) {
    return __uint_as_float(((unsigned)(unsigned short)h) << 16);
}

// ---------------------------------------------------------------------------
// Weight transpose: wT[m][c][o] = w_m[o][c]   (m: 0=q,1=k,2=v)
// ---------------------------------------------------------------------------
__global__ void wtrans_kernel(const float* __restrict__ wq,
                              const float* __restrict__ wk,
                              const float* __restrict__ wv,
                              float* __restrict__ wT) {
    int idx = blockIdx.x * 256 + threadIdx.x;   // 3*256*256 = 196608
    int o = idx & 255, c = (idx >> 8) & 255, m = idx >> 16;
    const float* w = (m == 0) ? wq : (m == 1) ? wk : wv;
    wT[idx] = w[o * 256 + c];
}

// ---------------------------------------------------------------------------
// pos -> Q' upper half [32:64), bf16 hi/lo.  grid (27, HEADS, B_), block 256.
// ---------------------------------------------------------------------------
__global__ void pos_kernel(const float* __restrict__ rel_d,
                           const float* __restrict__ rel_h,
                           const float* __restrict__ rel_w,
                           short* __restrict__ QhiT, short* __restrict__ QloT) {
    int t = threadIdx.x;
    int nl = t & 63, dd0 = (t >> 6) * 8;
    int n = blockIdx.x * 64 + nl;
    int h = blockIdx.y, b = blockIdx.z;
    int bh = b * HEADS + h;
    int di = n / 144, wi = (n / 12) % 12, hi = n % 12;
    union { short s[8]; uint4 v; } ph, pl;
    #pragma unroll
    for (int o = 0; o < 8; o++) {
        int hd = h * DK + dd0 + o;
        float val = rel_d[hd * 12 + di] + rel_w[hd * 12 + wi] + rel_h[hd * 12 + hi];
        short hh = f2bf(val);
        ph.s[o] = hh;
        pl.s[o] = f2bf(val - bf2f(hh));
    }
    size_t rowoff = ((size_t)bh * NVOX + n) * DE;
    *(uint4*)&QhiT[rowoff + DK + dd0] = ph.v;
    *(uint4*)&QloT[rowoff + DK + dd0] = pl.v;
}

// ---------------------------------------------------------------------------
// Fused projection: x -> q,k,v for one head, 8 channels/thread, direct bf16
// hi/lo transposed outputs (no fp32 intermediate).
// grid (27, HEADS, B_), block 256: nl = t&63, dd-group = (t>>6)*8.
// ---------------------------------------------------------------------------
__global__ __launch_bounds__(256)
void fproj_kernel(const float* __restrict__ x, const float* __restrict__ wT,
                  const float* __restrict__ bq, const float* __restrict__ bk,
                  const float* __restrict__ bv,
                  short* __restrict__ QhiT, short* __restrict__ QloT,
                  short* __restrict__ KhiT, short* __restrict__ KloT,
                  short* __restrict__ Vbf) {
    int t = threadIdx.x;
    int nl = t & 63;
    int dd0 = __builtin_amdgcn_readfirstlane((t >> 6) * 8);  // wave-uniform
    int n = blockIdx.x * 64 + nl;
    int h = blockIdx.y, b = blockIdx.z;
    int bh = b * HEADS + h;
    int obase = h * DK + dd0;
    const float* xb = x + (size_t)b * C_ * NVOX + n;

    float accq[8] = {}, acck[8] = {}, accv[8] = {};
    #pragma unroll 2
    for (int c = 0; c < C_; c++) {
        float xv = xb[(size_t)c * NVOX];
        const float* wtc = wT + (size_t)c * C_ + obase;
        #pragma unroll
        for (int o = 0; o < 8; o++) {
            accq[o] = fmaf(xv, wtc[o], accq[o]);
            acck[o] = fmaf(xv, wtc[65536 + o], acck[o]);
            accv[o] = fmaf(xv, wtc[131072 + o], accv[o]);
        }
    }

    union { short s[8]; uint4 v; } qh, ql, kh, kl;
    #pragma unroll
    for (int o = 0; o < 8; o++) {
        float qv = accq[o] + bq[obase + o];
        short hh = f2bf(qv);
        qh.s[o] = hh;
        ql.s[o] = f2bf(qv - bf2f(hh));
    }
    #pragma unroll
    for (int o = 0; o < 8; o++) {
        float kv = acck[o] + bk[obase + o];
        short hh = f2bf(kv);
        kh.s[o] = hh;
        kl.s[o] = f2bf(kv - bf2f(hh));
    }
    size_t rowoff = ((size_t)bh * NVOX + n) * DE;
    *(uint4*)&QhiT[rowoff + dd0] = qh.v;
    *(uint4*)&QloT[rowoff + dd0] = ql.v;
    *(uint4*)&KhiT[rowoff + dd0] = kh.v;
    *(uint4*)&KloT[rowoff + dd0] = kl.v;
    *(uint4*)&KhiT[rowoff + DK + dd0] = qh.v;   // K' upper = q
    *(uint4*)&KloT[rowoff + DK + dd0] = ql.v;
    #pragma unroll
    for (int o = 0; o < 8; o++) {
        float vv = accv[o] + bv[obase + o];
        Vbf[((size_t)bh * DK + dd0 + o) * NVOX + n] = f2bf(vv);
    }
}

// ---------------------------------------------------------------------------
// Flash attention partial, 32x32x16 bf16 MFMA, S^T orientation, j-split in 2.
// grid (36, HEADS, B_): it = bx>>1, jh = bx&1.  Block 192 (3 waves x 32 i).
// Writes unnormalized O^T + (m,l) partials to ws.
// ---------------------------------------------------------------------------
struct SMem {
    short Khi[64][PITCH];
    short Klo[64][PITCH];
    short V[DK][PITCH];
    short P[96][PITCH];
};

__device__ inline f32x16 mfma32(bf16x8 a, bf16x8 b, f32x16 c) {
    return __builtin_amdgcn_mfma_f32_32x32x16_bf16(a, b, c, 0, 0, 0);
}

__global__ __launch_bounds__(192, 3)
void attn_kernel(const short* __restrict__ QhiT, const short* __restrict__ QloT,
                 const short* __restrict__ KhiT, const short* __restrict__ KloT,
                 const short* __restrict__ Vbf,
                 float* __restrict__ wsO, float* __restrict__ wsM,
                 float* __restrict__ wsL) {
    __shared__ SMem sm;
    int bx = blockIdx.x;
    int it = bx >> 1, jh = bx & 1;
    int h = blockIdx.y, b = blockIdx.z;
    int bh = b * HEADS + h;
    int t = threadIdx.x;
    int w  = t >> 6;
    int l  = t & 63;
    int ln = l & 31;
    int hv = l >> 5;
    int i_loc  = w * 32 + ln;
    int i_glob = it * 96 + i_loc;

    const short* Qh = QhiT + (size_t)bh * NVOX * DE;
    const short* Ql = QloT + (size_t)bh * NVOX * DE;
    const short* Kh = KhiT + (size_t)bh * NVOX * DE;
    const short* Kl = KloT + (size_t)bh * NVOX * DE;
    const short* Vp = Vbf  + (size_t)bh * DK * NVOX;

    bf16x8 qfh[4], qfl[4];
    #pragma unroll
    for (int ks = 0; ks < 4; ks++) {
        size_t off = (size_t)i_glob * DE + ks * 16 + hv * 8;
        qfh[ks] = *(const bf16x8*)&Qh[off];
        qfl[ks] = *(const bf16x8*)&Ql[off];
    }

    float mL = -INFINITY;
    float lsum = 0.f;
    f32x16 O;
    #pragma unroll
    for (int r = 0; r < 16; r++) O[r] = 0.f;

    int jt0 = jh ? 14 : 0, jt1 = jh ? 27 : 14;
    #pragma unroll 1
    for (int jt = jt0; jt < jt1; jt++) {
        int jb = jt * 64;
        __syncthreads();
        for (int e = t; e < 512; e += 192) {
            int row = e >> 3, c = (e & 7) * 8;
            *(uint4*)&sm.Khi[row][c] = *(const uint4*)&Kh[(size_t)(jb + row) * DE + c];
            *(uint4*)&sm.Klo[row][c] = *(const uint4*)&Kl[(size_t)(jb + row) * DE + c];
        }
        for (int e = t; e < 256; e += 192) {
            int d = e >> 3, c = (e & 7) * 8;
            *(uint4*)&sm.V[d][c] = *(const uint4*)&Vp[(size_t)d * NVOX + jb + c];
        }
        __syncthreads();

        f32x16 sc[2];
        #pragma unroll
        for (int js = 0; js < 2; js++) {
            f32x16 s;
            #pragma unroll
            for (int r = 0; r < 16; r++) s[r] = 0.f;
            #pragma unroll
            for (int ks = 0; ks < 4; ks++) {
                bf16x8 kh = *(const bf16x8*)&sm.Khi[js * 32 + ln][ks * 16 + hv * 8];
                bf16x8 kl = *(const bf16x8*)&sm.Klo[js * 32 + ln][ks * 16 + hv * 8];
                s = mfma32(kh, qfh[ks], s);
                s = mfma32(kh, qfl[ks], s);
                s = mfma32(kl, qfh[ks], s);
            }
            sc[js] = s;
        }

        float mx = sc[0][0];
        #pragma unroll
        for (int js = 0; js < 2; js++)
            #pragma unroll
            for (int r = 0; r < 16; r++) mx = fmaxf(mx, sc[js][r]);
        mx = fmaxf(mx, __shfl_xor(mx, 32));
        float mLn = fmaxf(mL, mx * LOG2E);
        float alpha = exp2f(mL - mLn);
        mL = mLn;
        float ps = 0.f;
        #pragma unroll
        for (int js = 0; js < 2; js++)
            #pragma unroll
            for (int r = 0; r < 16; r++) {
                float p = exp2f(fmaf(sc[js][r], LOG2E, -mLn));
                sc[js][r] = p;
                ps += p;
            }
        ps += __shfl_xor(ps, 32);
        lsum = lsum * alpha + ps;

        #pragma unroll
        for (int js = 0; js < 2; js++)
            #pragma unroll
            for (int g = 0; g < 4; g++) {
                unsigned u0 = __float_as_uint(sc[js][4 * g + 0]) + 0x8000u;
                unsigned u1 = __float_as_uint(sc[js][4 * g + 1]) + 0x8000u;
                unsigned u2 = __float_as_uint(sc[js][4 * g + 2]) + 0x8000u;
                unsigned u3 = __float_as_uint(sc[js][4 * g + 3]) + 0x8000u;
                uint2 pk;
                pk.x = __builtin_amdgcn_perm(u1, u0, 0x07060302);
                pk.y = __builtin_amdgcn_perm(u3, u2, 0x07060302);
                *(uint2*)&sm.P[i_loc][js * 32 + g * 8 + hv * 4] = pk;
            }

        #pragma unroll
        for (int r = 0; r < 16; r++) O[r] *= alpha;
        #pragma unroll
        for (int ks = 0; ks < 4; ks++) {
            bf16x8 va = *(const bf16x8*)&sm.V[ln][ks * 16 + hv * 8];
            bf16x8 pb = *(const bf16x8*)&sm.P[i_loc][ks * 16 + hv * 8];
            O = mfma32(va, pb, O);
        }
    }

    // ---- partial epilogue: unnormalized O^T + (m, l) ----
    float* Op = wsO + ((size_t)jh * (B_ * HEADS) + bh) * DK * NVOX;
    #pragma unroll
    for (int r = 0; r < 16; r++) {
        int d = (r & 3) + 8 * (r >> 2) + 4 * hv;
        Op[(size_t)d * NVOX + i_glob] = O[r];
    }
    if (hv == 0) {
        size_t mo = ((size_t)jh * (B_ * HEADS) + bh) * NVOX + i_glob;
        wsM[mo] = mL;
        wsL[mo] = lsum;
    }
}

// ---------------------------------------------------------------------------
// Combine the two j-half partials (flash merge identity).
// ---------------------------------------------------------------------------
__global__ void combine_kernel(const float* __restrict__ wsO,
                               const float* __restrict__ wsM,
                               const float* __restrict__ wsL,
                               float* __restrict__ out) {
    int idx = blockIdx.x * 256 + threadIdx.x;   // B_*HEADS*DK*NVOX = 1,769,472
    int i = idx % NVOX;
    int bh = (idx / NVOX) >> 5;
    const size_t ohalf = (size_t)B_ * HEADS * DK * NVOX;
    const size_t mhalf = (size_t)B_ * HEADS * NVOX;
    size_t mo = (size_t)bh * NVOX + i;
    float m1 = wsM[mo], m2 = wsM[mhalf + mo];
    float l1 = wsL[mo], l2 = wsL[mhalf + mo];
    float m = fmaxf(m1, m2);
    float a1 = exp2f(m1 - m), a2 = exp2f(m2 - m);
    float O1 = wsO[idx], O2 = wsO[ohalf + idx];
    out[idx] = (a1 * O1 + a2 * O2) / (a1 * l1 + a2 * l2);
}

// ---------------------------------------------------------------------------
extern "C" void kernel_launch(void* const* d_in, const int* in_sizes, int n_in,
                              void* d_out, int out_size, void* d_ws, size_t ws_size,
                              hipStream_t stream) {
    const float* x     = (const float*)d_in[0];
    const float* wq    = (const float*)d_in[1];
    const float* bq    = (const float*)d_in[2];
    const float* wk    = (const float*)d_in[3];
    const float* bk    = (const float*)d_in[4];
    const float* wv    = (const float*)d_in[5];
    const float* bv    = (const float*)d_in[6];
    const float* rel_d = (const float*)d_in[7];
    const float* rel_h = (const float*)d_in[8];
    const float* rel_w = (const float*)d_in[9];
    float* out = (float*)d_out;

    size_t qksz = (size_t)B_ * HEADS * NVOX * DE;        // 3,538,944 shorts
    size_t vsz  = (size_t)B_ * HEADS * DK * NVOX;        // 1,769,472
    short* QhiT = (short*)d_ws;
    short* QloT = QhiT + qksz;
    short* KhiT = QloT + qksz;
    short* KloT = KhiT + qksz;
    short* Vbf  = KloT + qksz;
    float* wT   = (float*)(Vbf + vsz);                   // 196,608 floats
    float* wsO  = wT + (size_t)3 * C_ * C_;              // 2*vsz floats
    float* wsM  = wsO + 2 * vsz;
    float* wsL  = wsM + 2 * (size_t)B_ * HEADS * NVOX;

    pos_kernel<<<dim3(NVOX / 64, HEADS, B_), dim3(256), 0, stream>>>(
        rel_d, rel_h, rel_w, QhiT, QloT);
    wtrans_kernel<<<dim3(3 * C_ * C_ / 256), dim3(256), 0, stream>>>(wq, wk, wv, wT);
    fproj_kernel<<<dim3(NVOX / 64, HEADS, B_), dim3(256), 0, stream>>>(
        x, wT, bq, bk, bv, QhiT, QloT, KhiT, KloT, Vbf);
    attn_kernel<<<dim3(2 * NVOX / 96, HEADS, B_), dim3(192), 0, stream>>>(
        QhiT, QloT, KhiT, KloT, Vbf, wsO, wsM, wsL);
    combine_kernel<<<dim3((int)(vsz / 256)), dim3(256), 0, stream>>>(wsO, wsM, wsL, out);
}

// Round 5
// 205.094 us; speedup vs baseline: 2.9722x; 1.1930x over previous
//
#include <hip/hip_runtime.h>
#include <math.h>

#define HEADS 8
#define DK 32
#define B_ 4
#define C_ 256
#define NVOX 1728   // 12*12*12
#define DE 64       // effective head dim: Q'=[q;pos], K'=[k;q]
#define PITCH 72    // attn LDS pitch (shorts)
#define XPITCH 264  // fproj x-tile LDS pitch (shorts): 528B, 16B-aligned, 4-way
#define CPITCH 36   // fproj cbuf pitch (floats): 144B, 16B-aligned
#define LOG2E 1.44269504088896f

typedef short bf16x8 __attribute__((ext_vector_type(8)));
typedef float f32x16 __attribute__((ext_vector_type(16)));

__device__ inline short f2bf(float x) {
    unsigned u = __float_as_uint(x);
    unsigned r = u + 0x7fffu + ((u >> 16) & 1u);
    return (short)(r >> 16);
}
__device__ inline float bf2f(short h) {
    return __uint_as_float(((unsigned)(unsigned short)h) << 16);
}
__device__ inline f32x16 mfma32(bf16x8 a, bf16x8 b, f32x16 c) {
    return __builtin_amdgcn_mfma_f32_32x32x16_bf16(a, b, c, 0, 0, 0);
}

// ---------------------------------------------------------------------------
// Weight hi/lo split (layout [mat][o][c], same as input w)
// ---------------------------------------------------------------------------
__global__ void wsplit_kernel(const float* __restrict__ wq,
                              const float* __restrict__ wk,
                              const float* __restrict__ wv,
                              short* __restrict__ whi, short* __restrict__ wlo) {
    int idx = blockIdx.x * 256 + threadIdx.x;   // 3*65536
    int m = idx >> 16;
    const float* w = (m == 0) ? wq : (m == 1) ? wk : wv;
    float v = w[idx & 65535];
    short h = f2bf(v);
    whi[idx] = h;
    wlo[idx] = f2bf(v - bf2f(h));
}

// ---------------------------------------------------------------------------
// x transpose + hi/lo split:  x[b][c][n] fp32 -> xbhi/xblo [b][n][c] bf16
// grid (27 n-tiles, 4 c-tiles, B_), block 256, LDS tile [64][65] fp32.
// ---------------------------------------------------------------------------
__global__ __launch_bounds__(256)
void xsplit_kernel(const float* __restrict__ x,
                   short* __restrict__ xbhi, short* __restrict__ xblo) {
    __shared__ float tile[64][65];
    int nb = blockIdx.x * 64, c0 = blockIdx.y * 64, b = blockIdx.z;
    int t = threadIdx.x;
    const float* xb = x + (size_t)b * C_ * NVOX;
    for (int e = t; e < 4096; e += 256) {
        int ci = e >> 6, nl = e & 63;
        tile[ci][nl] = xb[(size_t)(c0 + ci) * NVOX + nb + nl];
    }
    __syncthreads();
    for (int e = t; e < 512; e += 256) {
        int n = e >> 3, cg = (e & 7) * 8;
        union { short s[8]; uint4 v; } hi, lo;
        #pragma unroll
        for (int j = 0; j < 8; j++) {
            float v = tile[cg + j][n];
            short h = f2bf(v);
            hi.s[j] = h;
            lo.s[j] = f2bf(v - bf2f(h));
        }
        size_t off = ((size_t)b * NVOX + nb + n) * C_ + c0 + cg;
        *(uint4*)&xbhi[off] = hi.v;
        *(uint4*)&xblo[off] = lo.v;
    }
}

// ---------------------------------------------------------------------------
// pos -> Q' upper half [32:64), bf16 hi/lo.  grid (27, HEADS, B_), block 256.
// ---------------------------------------------------------------------------
__global__ void pos_kernel(const float* __restrict__ rel_d,
                           const float* __restrict__ rel_h,
                           const float* __restrict__ rel_w,
                           short* __restrict__ QhiT, short* __restrict__ QloT) {
    int t = threadIdx.x;
    int nl = t & 63, dd0 = (t >> 6) * 8;
    int n = blockIdx.x * 64 + nl;
    int h = blockIdx.y, b = blockIdx.z;
    int bh = b * HEADS + h;
    int di = n / 144, wi = (n / 12) % 12, hi = n % 12;
    union { short s[8]; uint4 v; } ph, pl;
    #pragma unroll
    for (int o = 0; o < 8; o++) {
        int hd = h * DK + dd0 + o;
        float val = rel_d[hd * 12 + di] + rel_w[hd * 12 + wi] + rel_h[hd * 12 + hi];
        short hh = f2bf(val);
        ph.s[o] = hh;
        pl.s[o] = f2bf(val - bf2f(hh));
    }
    size_t rowoff = ((size_t)bh * NVOX + n) * DE;
    *(uint4*)&QhiT[rowoff + DK + dd0] = ph.v;
    *(uint4*)&QloT[rowoff + DK + dd0] = pl.v;
}

// ---------------------------------------------------------------------------
// MFMA projection: out[o][n] = sum_c W[o][c] * XT[n][c]  (hi/lo split, 3 MFMA)
// grid (27 n-tiles, HEADS, B_), block 384 = 6 waves = 3 mats x 2 n-halves.
// Epilogue: C -> LDS cbuf[mat][n][o] -> bias + hi/lo pack -> global layouts.
// ---------------------------------------------------------------------------
struct FS {
    union {
        struct { short xhi[64 * XPITCH]; short xlo[64 * XPITCH]; } s;
        float cbuf[3][64][CPITCH];
    } u;
};

__global__ __launch_bounds__(384, 3)
void fproj_kernel(const short* __restrict__ xbhi, const short* __restrict__ xblo,
                  const short* __restrict__ whi, const short* __restrict__ wlo,
                  const float* __restrict__ bq, const float* __restrict__ bk,
                  const float* __restrict__ bv,
                  short* __restrict__ QhiT, short* __restrict__ QloT,
                  short* __restrict__ KhiT, short* __restrict__ KloT,
                  short* __restrict__ Vbf) {
    __shared__ FS sm;
    int nb = blockIdx.x * 64, h = blockIdx.y, b = blockIdx.z;
    int bh = b * HEADS + h;
    int t = threadIdx.x;
    int w = t >> 6, l = t & 63, ln = l & 31, hv = l >> 5;
    int mat = w >> 1, nh = w & 1;

    // stage x tile (hi/lo), rows n, pitch XPITCH
    const short* xh = xbhi + ((size_t)b * NVOX + nb) * C_;
    const short* xl = xblo + ((size_t)b * NVOX + nb) * C_;
    for (int e = t; e < 2048; e += 384) {
        int row = e >> 5, c8 = (e & 31) * 8;
        *(uint4*)&sm.u.s.xhi[row * XPITCH + c8] = *(const uint4*)&xh[row * C_ + c8];
        *(uint4*)&sm.u.s.xlo[row * XPITCH + c8] = *(const uint4*)&xl[row * C_ + c8];
    }
    __syncthreads();

    const short* wAh = whi + ((size_t)mat * C_ + h * DK + ln) * C_;
    const short* wAl = wlo + ((size_t)mat * C_ + h * DK + ln) * C_;
    int xrow = (nh * 32 + ln) * XPITCH;

    f32x16 acc;
    #pragma unroll
    for (int r = 0; r < 16; r++) acc[r] = 0.f;
    #pragma unroll 4
    for (int ks = 0; ks < 16; ks++) {
        int kc = ks * 16 + hv * 8;
        bf16x8 ah = *(const bf16x8*)&wAh[kc];
        bf16x8 al = *(const bf16x8*)&wAl[kc];
        bf16x8 bh = *(const bf16x8*)&sm.u.s.xhi[xrow + kc];
        bf16x8 bl = *(const bf16x8*)&sm.u.s.xlo[xrow + kc];
        acc = mfma32(ah, bh, acc);
        acc = mfma32(al, bh, acc);
        acc = mfma32(ah, bl, acc);
    }
    __syncthreads();   // x tiles dead; reuse as cbuf

    const float* bias = (mat == 0) ? bq : (mat == 1) ? bk : bv;
    int ncol = nh * 32 + ln;
    #pragma unroll
    for (int q2 = 0; q2 < 4; q2++) {
        float4 cv;
        float* cvp = (float*)&cv;
        #pragma unroll
        for (int m = 0; m < 4; m++) {
            int o_loc = 8 * q2 + 4 * hv + m;
            cvp[m] = acc[4 * q2 + m] + bias[h * DK + o_loc];
        }
        *(float4*)&sm.u.cbuf[mat][ncol][8 * q2 + 4 * hv] = cv;
    }
    __syncthreads();

    // ---- readout q/k: item (n = e>>2, ddg = (e&3)*8), 256 items ----
    if (t < 256) {
        int n = t >> 2, ddg = (t & 3) * 8;
        size_t rowoff = ((size_t)bh * NVOX + nb + n) * DE;
        union { short s[8]; uint4 v; } qh, ql, kh, kl;
        float4 qa = *(float4*)&sm.u.cbuf[0][n][ddg];
        float4 qb = *(float4*)&sm.u.cbuf[0][n][ddg + 4];
        float4 ka = *(float4*)&sm.u.cbuf[1][n][ddg];
        float4 kb = *(float4*)&sm.u.cbuf[1][n][ddg + 4];
        const float* qp = (const float*)&qa;
        const float* kp = (const float*)&ka;
        #pragma unroll
        for (int j = 0; j < 8; j++) {
            float qv = (j < 4) ? qp[j] : ((const float*)&qb)[j - 4];
            short hh = f2bf(qv);
            qh.s[j] = hh;
            ql.s[j] = f2bf(qv - bf2f(hh));
            float kv = (j < 4) ? kp[j] : ((const float*)&kb)[j - 4];
            short kk = f2bf(kv);
            kh.s[j] = kk;
            kl.s[j] = f2bf(kv - bf2f(kk));
        }
        *(uint4*)&QhiT[rowoff + ddg] = qh.v;
        *(uint4*)&QloT[rowoff + ddg] = ql.v;
        *(uint4*)&KhiT[rowoff + ddg] = kh.v;
        *(uint4*)&KloT[rowoff + ddg] = kl.v;
        *(uint4*)&KhiT[rowoff + DK + ddg] = qh.v;   // K' upper = q
        *(uint4*)&KloT[rowoff + DK + ddg] = ql.v;
    }
    // ---- readout v: item (d = e>>3, ng = (e&7)*8), 256 items ----
    if (t < 256) {
        int d = t >> 3, ng = (t & 7) * 8;
        union { short s[8]; uint4 v; } vv;
        #pragma unroll
        for (int j = 0; j < 8; j++)
            vv.s[j] = f2bf(sm.u.cbuf[2][ng + j][d]);
        *(uint4*)&Vbf[((size_t)bh * DK + d) * NVOX + nb + ng] = vv.v;
    }
}

// ---------------------------------------------------------------------------
// Flash attention partial, 32x32x16 bf16 MFMA, S^T orientation, j-split in 3.
// grid (54, HEADS, B_): it = bx/3, jp = bx%3.  Block 192 (3 waves x 32 i).
// ---------------------------------------------------------------------------
struct SMem {
    short Khi[64][PITCH];
    short Klo[64][PITCH];
    short V[DK][PITCH];
    short P[96][PITCH];
};

__global__ __launch_bounds__(192, 3)
void attn_kernel(const short* __restrict__ QhiT, const short* __restrict__ QloT,
                 const short* __restrict__ KhiT, const short* __restrict__ KloT,
                 const short* __restrict__ Vbf,
                 float* __restrict__ wsO, float* __restrict__ wsM,
                 float* __restrict__ wsL) {
    __shared__ SMem sm;
    int bx = blockIdx.x;
    int it = bx / 3, jp = bx % 3;
    int h = blockIdx.y, b = blockIdx.z;
    int bh = b * HEADS + h;
    int t = threadIdx.x;
    int w  = t >> 6;
    int l  = t & 63;
    int ln = l & 31;
    int hv = l >> 5;
    int i_loc  = w * 32 + ln;
    int i_glob = it * 96 + i_loc;

    const short* Qh = QhiT + (size_t)bh * NVOX * DE;
    const short* Ql = QloT + (size_t)bh * NVOX * DE;
    const short* Kh = KhiT + (size_t)bh * NVOX * DE;
    const short* Kl = KloT + (size_t)bh * NVOX * DE;
    const short* Vp = Vbf  + (size_t)bh * DK * NVOX;

    bf16x8 qfh[4], qfl[4];
    #pragma unroll
    for (int ks = 0; ks < 4; ks++) {
        size_t off = (size_t)i_glob * DE + ks * 16 + hv * 8;
        qfh[ks] = *(const bf16x8*)&Qh[off];
        qfl[ks] = *(const bf16x8*)&Ql[off];
    }

    float mL = -INFINITY;
    float lsum = 0.f;
    f32x16 O;
    #pragma unroll
    for (int r = 0; r < 16; r++) O[r] = 0.f;

    int jt0 = jp * 9, jt1 = jt0 + 9;
    #pragma unroll 1
    for (int jt = jt0; jt < jt1; jt++) {
        int jb = jt * 64;
        __syncthreads();
        for (int e = t; e < 512; e += 192) {
            int row = e >> 3, c = (e & 7) * 8;
            *(uint4*)&sm.Khi[row][c] = *(const uint4*)&Kh[(size_t)(jb + row) * DE + c];
            *(uint4*)&sm.Klo[row][c] = *(const uint4*)&Kl[(size_t)(jb + row) * DE + c];
        }
        for (int e = t; e < 256; e += 192) {
            int d = e >> 3, c = (e & 7) * 8;
            *(uint4*)&sm.V[d][c] = *(const uint4*)&Vp[(size_t)d * NVOX + jb + c];
        }
        __syncthreads();

        f32x16 sc[2];
        #pragma unroll
        for (int js = 0; js < 2; js++) {
            f32x16 s;
            #pragma unroll
            for (int r = 0; r < 16; r++) s[r] = 0.f;
            #pragma unroll
            for (int ks = 0; ks < 4; ks++) {
                bf16x8 kh = *(const bf16x8*)&sm.Khi[js * 32 + ln][ks * 16 + hv * 8];
                bf16x8 kl = *(const bf16x8*)&sm.Klo[js * 32 + ln][ks * 16 + hv * 8];
                s = mfma32(kh, qfh[ks], s);
                s = mfma32(kh, qfl[ks], s);
                s = mfma32(kl, qfh[ks], s);
            }
            sc[js] = s;
        }

        float mx = sc[0][0];
        #pragma unroll
        for (int js = 0; js < 2; js++)
            #pragma unroll
            for (int r = 0; r < 16; r++) mx = fmaxf(mx, sc[js][r]);
        mx = fmaxf(mx, __shfl_xor(mx, 32));
        float mLn = fmaxf(mL, mx * LOG2E);
        float alpha = exp2f(mL - mLn);
        mL = mLn;
        float ps = 0.f;
        #pragma unroll
        for (int js = 0; js < 2; js++)
            #pragma unroll
            for (int r = 0; r < 16; r++) {
                float p = exp2f(fmaf(sc[js][r], LOG2E, -mLn));
                sc[js][r] = p;
                ps += p;
            }
        ps += __shfl_xor(ps, 32);
        lsum = lsum * alpha + ps;

        #pragma unroll
        for (int js = 0; js < 2; js++)
            #pragma unroll
            for (int g = 0; g < 4; g++) {
                unsigned u0 = __float_as_uint(sc[js][4 * g + 0]) + 0x8000u;
                unsigned u1 = __float_as_uint(sc[js][4 * g + 1]) + 0x8000u;
                unsigned u2 = __float_as_uint(sc[js][4 * g + 2]) + 0x8000u;
                unsigned u3 = __float_as_uint(sc[js][4 * g + 3]) + 0x8000u;
                uint2 pk;
                pk.x = __builtin_amdgcn_perm(u1, u0, 0x07060302);
                pk.y = __builtin_amdgcn_perm(u3, u2, 0x07060302);
                *(uint2*)&sm.P[i_loc][js * 32 + g * 8 + hv * 4] = pk;
            }

        #pragma unroll
        for (int r = 0; r < 16; r++) O[r] *= alpha;
        #pragma unroll
        for (int ks = 0; ks < 4; ks++) {
            bf16x8 va = *(const bf16x8*)&sm.V[ln][ks * 16 + hv * 8];
            bf16x8 pb = *(const bf16x8*)&sm.P[i_loc][ks * 16 + hv * 8];
            O = mfma32(va, pb, O);
        }
    }

    float* Op = wsO + ((size_t)jp * (B_ * HEADS) + bh) * DK * NVOX;
    #pragma unroll
    for (int r = 0; r < 16; r++) {
        int d = (r & 3) + 8 * (r >> 2) + 4 * hv;
        Op[(size_t)d * NVOX + i_glob] = O[r];
    }
    if (hv == 0) {
        size_t mo = ((size_t)jp * (B_ * HEADS) + bh) * NVOX + i_glob;
        wsM[mo] = mL;
        wsL[mo] = lsum;
    }
}

// ---------------------------------------------------------------------------
// Combine the three j-third partials (flash merge identity).
// ---------------------------------------------------------------------------
__global__ void combine_kernel(const float* __restrict__ wsO,
                               const float* __restrict__ wsM,
                               const float* __restrict__ wsL,
                               float* __restrict__ out) {
    int idx = blockIdx.x * 256 + threadIdx.x;   // 1,769,472
    int i = idx % NVOX;
    int bh = (idx / NVOX) >> 5;
    const size_t oh = (size_t)B_ * HEADS * DK * NVOX;
    const size_t mh = (size_t)B_ * HEADS * NVOX;
    size_t mo = (size_t)bh * NVOX + i;
    float m0 = wsM[mo], m1 = wsM[mh + mo], m2 = wsM[2 * mh + mo];
    float m = fmaxf(fmaxf(m0, m1), m2);
    float a0 = exp2f(m0 - m), a1 = exp2f(m1 - m), a2 = exp2f(m2 - m);
    float num = a0 * wsO[idx] + a1 * wsO[oh + idx] + a2 * wsO[2 * oh + idx];
    float den = a0 * wsL[mo] + a1 * wsL[mh + mo] + a2 * wsL[2 * mh + mo];
    out[idx] = num / den;
}

// ---------------------------------------------------------------------------
extern "C" void kernel_launch(void* const* d_in, const int* in_sizes, int n_in,
                              void* d_out, int out_size, void* d_ws, size_t ws_size,
                              hipStream_t stream) {
    const float* x     = (const float*)d_in[0];
    const float* wq    = (const float*)d_in[1];
    const float* bq    = (const float*)d_in[2];
    const float* wk    = (const float*)d_in[3];
    const float* bk    = (const float*)d_in[4];
    const float* wv    = (const float*)d_in[5];
    const float* bv    = (const float*)d_in[6];
    const float* rel_d = (const float*)d_in[7];
    const float* rel_h = (const float*)d_in[8];
    const float* rel_w = (const float*)d_in[9];
    float* out = (float*)d_out;

    size_t qksz = (size_t)B_ * HEADS * NVOX * DE;        // 3,538,944 shorts
    size_t vsz  = (size_t)B_ * HEADS * DK * NVOX;        // 1,769,472
    short* QhiT = (short*)d_ws;
    short* QloT = QhiT + qksz;
    short* KhiT = QloT + qksz;
    short* KloT = KhiT + qksz;
    short* Vbf  = KloT + qksz;
    short* whi  = Vbf + vsz;                             // 196,608 shorts
    short* wlo  = whi + (size_t)3 * C_ * C_;
    float* wsO  = (float*)(wlo + (size_t)3 * C_ * C_);   // 3*vsz floats
    float* wsM  = wsO + 3 * vsz;                         // 3*B*H*NVOX
    float* wsL  = wsM + 3 * (size_t)B_ * HEADS * NVOX;
    // xbhi/xblo alias the wsO region (dead before attn writes it)
    short* xbhi = (short*)wsO;
    short* xblo = xbhi + (size_t)B_ * NVOX * C_;         // 1,769,472 shorts each

    wsplit_kernel<<<dim3(3 * C_ * C_ / 256), dim3(256), 0, stream>>>(wq, wk, wv, whi, wlo);
    xsplit_kernel<<<dim3(NVOX / 64, C_ / 64, B_), dim3(256), 0, stream>>>(x, xbhi, xblo);
    pos_kernel<<<dim3(NVOX / 64, HEADS, B_), dim3(256), 0, stream>>>(
        rel_d, rel_h, rel_w, QhiT, QloT);
    fproj_kernel<<<dim3(NVOX / 64, HEADS, B_), dim3(384), 0, stream>>>(
        xbhi, xblo, whi, wlo, bq, bk, bv, QhiT, QloT, KhiT, KloT, Vbf);
    attn_kernel<<<dim3(3 * NVOX / 96, HEADS, B_), dim3(192), 0, stream>>>(
        QhiT, QloT, KhiT, KloT, Vbf, wsO, wsM, wsL);
    combine_kernel<<<dim3((int)(vsz / 256)), dim3(256), 0, stream>>>(wsO, wsM, wsL, out);
}